// Round 1
// baseline (88.466 us; speedup 1.0000x reference)
//
#include <hip/hip_runtime.h>
#include <math.h>

// LossLayer: dist[b,r] = ||W[b]-R[r]||2 ; pred = one_hot(argmax_r dist) ;
// loss = mean(1 + dist[b,y] - dist[b, top2-excluding-y-at-top1]), y=argmax(label[b])
//
// R14 (occupancy experiment on R13): the 130 KB LDS re-tile forces 1
// block/CU; at 512 threads that is only 2 waves/SIMD. This version keeps
// ONE block/CU and the identical transposed+padded re layout, but runs
// 1024 threads (16 waves) and splits D across wave pairs: wave-pair wp
// (wp=wv&7) owns b-rows {b0+2wp, b0+2wp+1}; dh=wv>>3 selects d4 half
// [0,64) or [64,128). Aggregate LDS-read traffic, VALU work and HBM
// traffic are UNCHANGED (16 waves x 64 ds_reads == 8 waves x 128), but
// TLP doubles to 4 waves/SIMD. Partial sums combine via a 16 KB LDS
// exchange; epilogue (top-2/argmax/loss) runs on the dh==0 waves.
// Discriminator: if dur_us doesn't move, the measured time is the
// harness's 2x256MiB poison fills (top-5 dispatches), not the kernel.
#define NB 4096
#define NR 64
#define BBB 16          // b-rows per block; grid = 256 (1 block/CU)

typedef float f4v __attribute__((ext_vector_type(4)));

__global__ __launch_bounds__(1024) void fused_loss_kernel(
    const float* __restrict__ w,
    const float* __restrict__ re,
    const float* __restrict__ label,
    float* __restrict__ out,
    float* __restrict__ ws)
{
    __shared__ f4v rl[128 * 65];    // transposed+padded re: slot=d4*65+r, 130 KB
    __shared__ f4v xch[8][2][64];   // dh==1 partial accs: [wp][j][lane], 16 KB
    __shared__ float terms[8];

    const int tid = threadIdx.x;
    const int wv  = tid >> 6;       // wave id 0..15
    const int r   = tid & 63;       // lane = relation 0..63
    const int wp  = wv & 7;         // wave-pair id -> which 2 b-rows
    const int dh  = wv >> 3;        // d-half: 0 -> d4 [0,64), 1 -> [64,128)
    const int b0  = blockIdx.x * BBB;

    // ---- stage re row-major -> LDS transposed (one-time) ----
    // thread t, iter i: global f4 idx = i*1024+t; row=idx>>7, d4=idx&127.
    // Loads coalesced (1 KB/wave); ds_write banks rotate 4/lane (pad 65).
    const f4v* re4g = (const f4v*)re;
    #pragma unroll
    for (int i = 0; i < 8; i++) {
        int idx = i * 1024 + tid;
        f4v v = re4g[idx];                       // named temp, consumed at once
        rl[(idx & 127) * 65 + (idx >> 7)] = v;
    }

    // ---- hoisted label loads (only epilogue waves need them) ----
    const int b_0 = b0 + wp * 2;
    const int b_1 = b_0 + 1;
    float lv_0 = 0.0f, lv_1 = 0.0f;
    if (dh == 0) {                               // wave-uniform branch
        lv_0 = label[(size_t)b_0 * 64 + r];
        lv_1 = label[(size_t)b_1 * 64 + r];
    }

    // uniform W row pointers (readfirstlane -> scalar addr; broadcast data),
    // pre-offset to this wave's d-half
    const f4v* wr0;
    const f4v* wr1;
    {
        int bu0 = __builtin_amdgcn_readfirstlane(b_0);
        int bu1 = __builtin_amdgcn_readfirstlane(b_1);
        wr0 = (const f4v*)(w + (size_t)bu0 * 512) + dh * 64;
        wr1 = (const f4v*)(w + (size_t)bu1 * 512) + dh * 64;
    }

    f4v acc0 = {0.f, 0.f, 0.f, 0.f};
    f4v acc1 = {0.f, 0.f, 0.f, 0.f};

    __syncthreads();   // ONE drain: re resident+transposed; loop barrier-free

    // hot loop: 8 groups of 8 d4 within this wave's half. Per group:
    // 16 uniform W vector loads (vmcnt broadcast) + 8 lane-consecutive
    // ds_read_b128 (conflict-free) + packed-f32 FMA. unroll 2 keeps the
    // scheduler window inside the 128-VGPR budget at 4 waves/SIMD.
    const int d4base = dh * 64;
    #pragma unroll 2
    for (int g = 0; g < 8; g++) {
        const int gb = g * 8;

        f4v qa0 = wr0[gb+0], qa1 = wr0[gb+1], qa2 = wr0[gb+2], qa3 = wr0[gb+3];
        f4v qa4 = wr0[gb+4], qa5 = wr0[gb+5], qa6 = wr0[gb+6], qa7 = wr0[gb+7];
        f4v qb0 = wr1[gb+0], qb1 = wr1[gb+1], qb2 = wr1[gb+2], qb3 = wr1[gb+3];
        f4v qb4 = wr1[gb+4], qb5 = wr1[gb+5], qb6 = wr1[gb+6], qb7 = wr1[gb+7];

        const f4v* rp = &rl[(d4base + gb) * 65 + r];   // slot=(d4)*65+r
        f4v v0 = rp[0*65], v1 = rp[1*65], v2 = rp[2*65], v3 = rp[3*65];
        f4v v4 = rp[4*65], v5 = rp[5*65], v6 = rp[6*65], v7 = rp[7*65];

#define STEP(qa, qb, vv)                                                     \
        {                                                                    \
            f4v dxa = qa - vv;  acc0 = dxa * dxa + acc0;                     \
            f4v dxb = qb - vv;  acc1 = dxb * dxb + acc1;                     \
        }
        STEP(qa0, qb0, v0) STEP(qa1, qb1, v1) STEP(qa2, qb2, v2) STEP(qa3, qb3, v3)
        STEP(qa4, qb4, v4) STEP(qa5, qb5, v5) STEP(qa6, qb6, v6) STEP(qa7, qb7, v7)
#undef STEP
    }

    // ---- combine d-halves: dh==1 publishes, dh==0 reduces ----
    if (dh == 1) {
        xch[wp][0][r] = acc0;
        xch[wp][1][r] = acc1;
    }
    __syncthreads();

    float lsum = 0.0f;
    if (dh == 0) {
        acc0 = acc0 + xch[wp][0][r];
        acc1 = acc1 + xch[wp][1][r];

        // ---- epilogue per j: top-2/argmax + label argmax + loss term ----
        #pragma unroll
        for (int j = 0; j < 2; j++) {
            int b = (j == 0) ? b_0 : b_1;
            f4v accj = (j == 0) ? acc0 : acc1;
            float d = sqrtf((accj.x + accj.y) + (accj.z + accj.w));

            float m1 = d; int i1 = r; float m2 = -3.0e38f;
            #pragma unroll
            for (int mask = 1; mask <= 32; mask <<= 1) {
                float om1 = __shfl_xor(m1, mask, 64);
                int   oi1 = __shfl_xor(i1, mask, 64);
                float om2 = __shfl_xor(m2, mask, 64);
                bool ob1 = (om1 > m1) || (om1 == m1 && oi1 < i1);
                float w1 = ob1 ? om1 : m1;  int wi1 = ob1 ? oi1 : i1;
                float l1_ = ob1 ? m1 : om1;         // loser's top-1 (value only)
                float c2 = ob1 ? om2 : m2;          // winner's top-2 (value only)
                m1 = w1; i1 = wi1;
                m2 = (c2 > l1_) ? c2 : l1_;
            }

            float lv = (j == 0) ? lv_0 : lv_1; int ly = r;
            #pragma unroll
            for (int mask = 1; mask <= 32; mask <<= 1) {
                float ov = __shfl_xor(lv, mask, 64);
                int   oy = __shfl_xor(ly, mask, 64);
                if (ov > lv || (ov == lv && oy < ly)) { lv = ov; ly = oy; }
            }
            int y = ly;

            float plus  = __shfl(d, y, 64);       // dist[b][y]
            float minus = (i1 == y) ? m2 : m1;    // top-2 value if top-1 == y
            lsum += 1.0f + plus - minus;

            out[(size_t)b * 64 + r] = (i1 == r) ? 1.0f : 0.0f;   // pred one-hot
        }

        if (r == 0) terms[wp] = lsum;
    }

    // ---- fused loss reduction: block partial -> device atomic -> last block
    __syncthreads();
    if (tid == 0) {
        float t = (((terms[0] + terms[1]) + (terms[2] + terms[3]))
                 + ((terms[4] + terms[5]) + (terms[6] + terms[7]))) * (1.0f / NB);
        atomicAdd(ws, t);                     // ws[0] = loss accumulator (zeroed)
        __threadfence();                      // order add before counter inc
        unsigned old = atomicAdd((unsigned*)(ws + 1), 1u);   // ws[1] = counter
        if (old == (unsigned)(gridDim.x - 1)) {
            float total = atomicAdd(ws, 0.0f);   // all 256 adds visible
            out[(size_t)NB * NR] = total;
        }
    }
}

extern "C" void kernel_launch(void* const* d_in, const int* in_sizes, int n_in,
                              void* d_out, int out_size, void* d_ws, size_t ws_size,
                              hipStream_t stream) {
    const float* w   = (const float*)d_in[0];   // [4096,512]
    const float* re  = (const float*)d_in[1];   // [64,512]
    const float* lab = (const float*)d_in[2];   // [4096,64]
    float* out = (float*)d_out;                 // pred [4096,64] ++ loss [1]
    float* ws  = (float*)d_ws;                  // [0]=loss acc, [1]=done counter

    hipMemsetAsync(ws, 0, 8, stream);           // zero acc + counter (graph-safe)
    fused_loss_kernel<<<NB / BBB, 1024, 0, stream>>>(w, re, lab, out, ws);
}

// Round 2
// 87.632 us; speedup vs baseline: 1.0095x; 1.0095x over previous
//
#include <hip/hip_runtime.h>
#include <math.h>

// LossLayer: dist[b,r] = ||W[b]-R[r]||2 ; pred = one_hot(argmax_r dist) ;
// loss = mean(1 + dist[b,y] - dist[b, top2-excluding-y-at-top1]), y=argmax(label[b])
//
// R15 = R13 structure (512 thr, JB=2, unroll 4, transposed+padded re in LDS)
// with ONE change: the W row pointers are NO LONGER readfirstlane-uniformed.
// Theory: the provably-uniform SGPR address let LLVM promote the 256/wave W
// loads to s_load (SMEM). SMEM shares lgkmcnt with ds_read and returns
// in-order, so mixing s_loads with the hot loop's ds_reads forces
// conservative lgkmcnt(0) drains -> the streaming-W HBM latency (~900 cyc)
// is exposed once per group instead of pipelined (K ~= 39 us vs ~10 us
// throughput model). The empty asm forces the row index into a VGPR, making
// the address formally divergent -> global_load_dwordx4 on vmcnt: broadcast
// coalesced (one 16B request/wave), out-of-order, decoupled from DS waits.
#define NB 4096
#define NR 64
#define JB 2            // b-rows per wave
#define WVS 8           // waves per block (512 threads)
#define BBB (JB * WVS)  // 16 b-rows per block; grid = 256

typedef float f4v __attribute__((ext_vector_type(4)));

__global__ __launch_bounds__(512) void fused_loss_kernel(
    const float* __restrict__ w,
    const float* __restrict__ re,
    const float* __restrict__ label,
    float* __restrict__ out,
    float* __restrict__ ws)
{
    __shared__ f4v rl[128 * 65];    // transposed+padded re: slot=d4*65+r, 130 KB
    __shared__ float terms[WVS];

    const int tid = threadIdx.x;
    const int wv  = tid >> 6;       // wave id 0..7
    const int r   = tid & 63;       // lane = relation 0..63
    const int b0  = blockIdx.x * BBB;

    // ---- stage re row-major -> LDS transposed (one-time) ----
    // thread t, iter i: global f4 idx = i*512+t; row=idx>>7, d4=idx&127.
    // Loads coalesced (1 KB/wave); ds_write banks rotate 4/lane (pad 65).
    const f4v* re4g = (const f4v*)re;
    #pragma unroll
    for (int i = 0; i < 16; i++) {
        int idx = i * 512 + tid;
        f4v v = re4g[idx];                       // named temp, consumed at once
        rl[(idx & 127) * 65 + (idx >> 7)] = v;
    }

    // ---- hoisted label loads (latency hidden under staging) ----
    const int b_0 = b0 + wv * JB;
    const int b_1 = b_0 + 1;
    float lv_0 = label[(size_t)b_0 * 64 + r];
    float lv_1 = label[(size_t)b_1 * 64 + r];

    // W row pointers: wave-uniform IN FACT, but forced through a VGPR so the
    // compiler cannot prove uniformity -> VMEM (vmcnt) loads, not SMEM
    // (lgkmcnt). Keeps the DS counter private to the ds_reads in the loop.
    int bv0 = b_0, bv1 = b_1;
    asm volatile("" : "+v"(bv0), "+v"(bv1));     // defeat uniformity proof
    const f4v* wr0 = (const f4v*)(w + (size_t)bv0 * 512);
    const f4v* wr1 = (const f4v*)(w + (size_t)bv1 * 512);

    f4v acc0 = {0.f, 0.f, 0.f, 0.f};
    f4v acc1 = {0.f, 0.f, 0.f, 0.f};

    __syncthreads();   // ONE drain: re resident+transposed; loop barrier-free

    // hot loop: 16 groups of 8 d4. Per group: 16 broadcast W vector loads
    // (vmcnt, imm-offset folded) + 8 lane-consecutive ds_read_b128
    // (conflict-free) + packed-f32 FMA. unroll-4 gives a hoisting window.
    #pragma unroll 4
    for (int g = 0; g < 16; g++) {
        const int gb = g * 8;

        f4v qa0 = wr0[gb+0], qa1 = wr0[gb+1], qa2 = wr0[gb+2], qa3 = wr0[gb+3];
        f4v qa4 = wr0[gb+4], qa5 = wr0[gb+5], qa6 = wr0[gb+6], qa7 = wr0[gb+7];
        f4v qb0 = wr1[gb+0], qb1 = wr1[gb+1], qb2 = wr1[gb+2], qb3 = wr1[gb+3];
        f4v qb4 = wr1[gb+4], qb5 = wr1[gb+5], qb6 = wr1[gb+6], qb7 = wr1[gb+7];

        const f4v* rp = &rl[gb * 65 + r];        // slot=(gb+k)*65+r
        f4v v0 = rp[0*65], v1 = rp[1*65], v2 = rp[2*65], v3 = rp[3*65];
        f4v v4 = rp[4*65], v5 = rp[5*65], v6 = rp[6*65], v7 = rp[7*65];

#define STEP(qa, qb, vv)                                                     \
        {                                                                    \
            f4v dxa = qa - vv;  acc0 = dxa * dxa + acc0;                     \
            f4v dxb = qb - vv;  acc1 = dxb * dxb + acc1;                     \
        }
        STEP(qa0, qb0, v0) STEP(qa1, qb1, v1) STEP(qa2, qb2, v2) STEP(qa3, qb3, v3)
        STEP(qa4, qb4, v4) STEP(qa5, qb5, v5) STEP(qa6, qb6, v6) STEP(qa7, qb7, v7)
#undef STEP
    }

    // ---- epilogue per j: top-2/argmax + label argmax + loss term ----
    float lsum = 0.0f;
    #pragma unroll
    for (int j = 0; j < JB; j++) {
        int b = (j == 0) ? b_0 : b_1;
        f4v accj = (j == 0) ? acc0 : acc1;
        float d = sqrtf((accj.x + accj.y) + (accj.z + accj.w));

        float m1 = d; int i1 = r; float m2 = -3.0e38f;
        #pragma unroll
        for (int mask = 1; mask <= 32; mask <<= 1) {
            float om1 = __shfl_xor(m1, mask, 64);
            int   oi1 = __shfl_xor(i1, mask, 64);
            float om2 = __shfl_xor(m2, mask, 64);
            bool ob1 = (om1 > m1) || (om1 == m1 && oi1 < i1);
            float w1 = ob1 ? om1 : m1;  int wi1 = ob1 ? oi1 : i1;
            float l1_ = ob1 ? m1 : om1;         // loser's top-1 (value only)
            float c2 = ob1 ? om2 : m2;          // winner's top-2 (value only)
            m1 = w1; i1 = wi1;
            m2 = (c2 > l1_) ? c2 : l1_;
        }

        float lv = (j == 0) ? lv_0 : lv_1; int ly = r;
        #pragma unroll
        for (int mask = 1; mask <= 32; mask <<= 1) {
            float ov = __shfl_xor(lv, mask, 64);
            int   oy = __shfl_xor(ly, mask, 64);
            if (ov > lv || (ov == lv && oy < ly)) { lv = ov; ly = oy; }
        }
        int y = ly;

        float plus  = __shfl(d, y, 64);       // dist[b][y]
        float minus = (i1 == y) ? m2 : m1;    // top-2 value if top-1 == y
        lsum += 1.0f + plus - minus;

        out[(size_t)b * 64 + r] = (i1 == r) ? 1.0f : 0.0f;   // pred one-hot
    }

    if (r == 0) terms[wv] = lsum;

    // ---- fused loss reduction: block partial -> device atomic -> last block
    __syncthreads();
    if (tid == 0) {
        float t = (((terms[0] + terms[1]) + (terms[2] + terms[3]))
                 + ((terms[4] + terms[5]) + (terms[6] + terms[7]))) * (1.0f / NB);
        atomicAdd(ws, t);                     // ws[0] = loss accumulator (zeroed)
        __threadfence();                      // order add before counter inc
        unsigned old = atomicAdd((unsigned*)(ws + 1), 1u);   // ws[1] = counter
        if (old == (unsigned)(gridDim.x - 1)) {
            float total = atomicAdd(ws, 0.0f);   // all 256 adds visible
            out[(size_t)NB * NR] = total;
        }
    }
}

extern "C" void kernel_launch(void* const* d_in, const int* in_sizes, int n_in,
                              void* d_out, int out_size, void* d_ws, size_t ws_size,
                              hipStream_t stream) {
    const float* w   = (const float*)d_in[0];   // [4096,512]
    const float* re  = (const float*)d_in[1];   // [64,512]
    const float* lab = (const float*)d_in[2];   // [4096,64]
    float* out = (float*)d_out;                 // pred [4096,64] ++ loss [1]
    float* ws  = (float*)d_ws;                  // [0]=loss acc, [1]=done counter

    hipMemsetAsync(ws, 0, 8, stream);           // zero acc + counter (graph-safe)
    fused_loss_kernel<<<NB / BBB, 512, 0, stream>>>(w, re, lab, out, ws);
}

// Round 3
// 82.941 us; speedup vs baseline: 1.0666x; 1.0566x over previous
//
#include <hip/hip_runtime.h>
#include <math.h>

// LossLayer: dist[b,r] = ||W[b]-R[r]||2 ; pred = one_hot(argmax_r dist) ;
// loss = mean(1 + dist[b,y] - dist[b, top2-excluding-y-at-top1]), y=argmax(label[b])
//
// R16: kill the broadcast-W latency wall. In R13/R15 the hot loop's W loads
// were wave-uniform: 64 lanes x same 16 B -> ONE 16-B request in flight per
// instruction. Little's law: 6.3 TB/s x 900 cyc needs ~2.4 MB in flight;
// broadcast chains give ~8 KB/CU -> effective W stream ~0.7 TB/s -> 8 MB of
// W costs >11 us + per-group stalls. Fix: stage W through LDS coalesced
// (each wave copies its 2 contiguous rows, 4 x 1KB lane-distinct loads, all
// in flight at once), hot loop reads W as LDS broadcast (same-addr = free).
// LDS budget: re tile re-laid pad-free with XOR swizzle
//   slot = d4*64 + (row ^ (d4&7))   (128 KB)
// writes stay 8-way-conflicted one-time (same as old pad-65); hot reads stay
// conflict-free: group base gb%8==0 -> (gb+k)&7 == k compile-time, lanes read
// a full permuted 1 KB row. + 32 KB W slices = exactly 160 KiB (AITER attn
// uses 160 KB/block on gfx950). terms reuse each wave's dead W slice.
#define NB 4096
#define NR 64
#define JB 2            // b-rows per wave
#define WVS 8           // waves per block (512 threads)
#define BBB (JB * WVS)  // 16 b-rows per block; grid = 256

typedef float f4v __attribute__((ext_vector_type(4)));

__global__ __launch_bounds__(512) void fused_loss_kernel(
    const float* __restrict__ w,
    const float* __restrict__ re,
    const float* __restrict__ label,
    float* __restrict__ out,
    float* __restrict__ ws)
{
    __shared__ f4v rl[128 * 64];    // transposed+swizzled re: 128 KB
    __shared__ f4v wl[WVS * 256];   // per-wave W slices (2 rows each): 32 KB

    const int tid = threadIdx.x;
    const int wv  = tid >> 6;       // wave id 0..7
    const int r   = tid & 63;       // lane = relation 0..63
    const int b0  = blockIdx.x * BBB;

    // ---- stage re row-major -> LDS transposed + XOR-swizzled (one-time) ----
    // thread t, iter i: global f4 idx = i*512+t; row=idx>>7, d4=idx&127.
    // Loads coalesced (1 KB/wave); writes 8-way conflicted (one-time, cheap).
    const f4v* re4g = (const f4v*)re;
    #pragma unroll
    for (int i = 0; i < 16; i++) {
        int idx = i * 512 + tid;
        int d4 = idx & 127, row = idx >> 7;
        f4v v = re4g[idx];                       // named temp, consumed at once
        rl[d4 * 64 + (row ^ (d4 & 7))] = v;
    }

    // ---- stage this wave's 2 W rows -> wave-private LDS slice (coalesced) ----
    // rows b_0,b_1 are contiguous: one 4 KB span, 4 lane-distinct 1 KB loads.
    const int b_0 = b0 + wv * JB;
    const int b_1 = b_0 + 1;
    f4v* wls = &wl[wv * 256];
    {
        const f4v* src = (const f4v*)w + (size_t)b_0 * 128;
        #pragma unroll
        for (int k2 = 0; k2 < 4; k2++) {
            int o = k2 * 64 + r;
            f4v v = src[o];                      // coalesced, deep in flight
            wls[o] = v;                          // conflict-free ds_write
        }
    }

    // ---- hoisted label loads (latency hidden under staging) ----
    float lv_0 = label[(size_t)b_0 * 64 + r];
    float lv_1 = label[(size_t)b_1 * 64 + r];

    f4v acc0 = {0.f, 0.f, 0.f, 0.f};
    f4v acc1 = {0.f, 0.f, 0.f, 0.f};

    __syncthreads();   // rl resident (wl is wave-private: same-wave lgkmcnt ordering)

    // hot loop: 16 groups of 8 d4. Per group: 16 broadcast W ds_reads (same
    // addr -> conflict-free) + 8 permuted-row re ds_reads (conflict-free) +
    // packed-f32 FMA. No global memory in the loop at all.
    #pragma unroll 4
    for (int g = 0; g < 16; g++) {
        const int gb = g * 8;
        const f4v* wa = &wls[gb];                // row b_0 chunk
        const f4v* wb = &wls[128 + gb];          // row b_1 chunk

        f4v qa0 = wa[0], qa1 = wa[1], qa2 = wa[2], qa3 = wa[3];
        f4v qa4 = wa[4], qa5 = wa[5], qa6 = wa[6], qa7 = wa[7];
        f4v qb0 = wb[0], qb1 = wb[1], qb2 = wb[2], qb3 = wb[3];
        f4v qb4 = wb[4], qb5 = wb[5], qb6 = wb[6], qb7 = wb[7];

        // re reads: slot = (gb+k)*64 + (r ^ k)  ((gb+k)&7 == k, compile-time)
        f4v v0 = rl[(gb+0)*64 + (r^0)], v1 = rl[(gb+1)*64 + (r^1)];
        f4v v2 = rl[(gb+2)*64 + (r^2)], v3 = rl[(gb+3)*64 + (r^3)];
        f4v v4 = rl[(gb+4)*64 + (r^4)], v5 = rl[(gb+5)*64 + (r^5)];
        f4v v6 = rl[(gb+6)*64 + (r^6)], v7 = rl[(gb+7)*64 + (r^7)];

#define STEP(qa, qb, vv)                                                     \
        {                                                                    \
            f4v dxa = qa - vv;  acc0 = dxa * dxa + acc0;                     \
            f4v dxb = qb - vv;  acc1 = dxb * dxb + acc1;                     \
        }
        STEP(qa0, qb0, v0) STEP(qa1, qb1, v1) STEP(qa2, qb2, v2) STEP(qa3, qb3, v3)
        STEP(qa4, qb4, v4) STEP(qa5, qb5, v5) STEP(qa6, qb6, v6) STEP(qa7, qb7, v7)
#undef STEP
    }

    // ---- epilogue per j: top-2/argmax + label argmax + loss term ----
    float lsum = 0.0f;
    #pragma unroll
    for (int j = 0; j < JB; j++) {
        int b = (j == 0) ? b_0 : b_1;
        f4v accj = (j == 0) ? acc0 : acc1;
        float d = sqrtf((accj.x + accj.y) + (accj.z + accj.w));

        float m1 = d; int i1 = r; float m2 = -3.0e38f;
        #pragma unroll
        for (int mask = 1; mask <= 32; mask <<= 1) {
            float om1 = __shfl_xor(m1, mask, 64);
            int   oi1 = __shfl_xor(i1, mask, 64);
            float om2 = __shfl_xor(m2, mask, 64);
            bool ob1 = (om1 > m1) || (om1 == m1 && oi1 < i1);
            float w1 = ob1 ? om1 : m1;  int wi1 = ob1 ? oi1 : i1;
            float l1_ = ob1 ? m1 : om1;         // loser's top-1 (value only)
            float c2 = ob1 ? om2 : m2;          // winner's top-2 (value only)
            m1 = w1; i1 = wi1;
            m2 = (c2 > l1_) ? c2 : l1_;
        }

        float lv = (j == 0) ? lv_0 : lv_1; int ly = r;
        #pragma unroll
        for (int mask = 1; mask <= 32; mask <<= 1) {
            float ov = __shfl_xor(lv, mask, 64);
            int   oy = __shfl_xor(ly, mask, 64);
            if (ov > lv || (ov == lv && oy < ly)) { lv = ov; ly = oy; }
        }
        int y = ly;

        float plus  = __shfl(d, y, 64);       // dist[b][y]
        float minus = (i1 == y) ? m2 : m1;    // top-2 value if top-1 == y
        lsum += 1.0f + plus - minus;

        out[(size_t)b * 64 + r] = (i1 == r) ? 1.0f : 0.0f;   // pred one-hot
    }

    // term -> first float of this wave's OWN (now dead) W slice: no race.
    if (r == 0) ((float*)wls)[0] = lsum;

    // ---- fused loss reduction: block partial -> device atomic -> last block
    __syncthreads();
    if (tid == 0) {
        const float* tf = (const float*)wl;   // terms at float stride 1024
        float t = (((tf[0] + tf[1024]) + (tf[2048] + tf[3072]))
                 + ((tf[4096] + tf[5120]) + (tf[6144] + tf[7168]))) * (1.0f / NB);
        atomicAdd(ws, t);                     // ws[0] = loss accumulator (zeroed)
        __threadfence();                      // order add before counter inc
        unsigned old = atomicAdd((unsigned*)(ws + 1), 1u);   // ws[1] = counter
        if (old == (unsigned)(gridDim.x - 1)) {
            float total = atomicAdd(ws, 0.0f);   // all 256 adds visible
            out[(size_t)NB * NR] = total;
        }
    }
}

extern "C" void kernel_launch(void* const* d_in, const int* in_sizes, int n_in,
                              void* d_out, int out_size, void* d_ws, size_t ws_size,
                              hipStream_t stream) {
    const float* w   = (const float*)d_in[0];   // [4096,512]
    const float* re  = (const float*)d_in[1];   // [64,512]
    const float* lab = (const float*)d_in[2];   // [4096,64]
    float* out = (float*)d_out;                 // pred [4096,64] ++ loss [1]
    float* ws  = (float*)d_ws;                  // [0]=loss acc, [1]=done counter

    hipMemsetAsync(ws, 0, 8, stream);           // zero acc + counter (graph-safe)
    fused_loss_kernel<<<NB / BBB, 512, 0, stream>>>(w, re, lab, out, ws);
}